// Round 10
// baseline (645.524 us; speedup 1.0000x reference)
//
#include <hip/hip_runtime.h>
#include <math.h>

#define C_   512
#define C8_  64
#define HH   96
#define WW   96
#define PP   9216            // HH*WW
#define CP   4718592         // C_*PP
#define C8P  589824          // C8_*PP

typedef __attribute__((ext_vector_type(4))) float f32x4;
typedef __attribute__((ext_vector_type(8))) __bf16 bf16x8;
typedef __attribute__((ext_vector_type(8))) unsigned short ushort8;
typedef __attribute__((ext_vector_type(4))) unsigned short ushort4v;
typedef __attribute__((ext_vector_type(2))) unsigned short ushort2v;
typedef __attribute__((ext_vector_type(2))) float float2v;

__device__ __forceinline__ float bf2f(unsigned short u) {
    union { unsigned u; float f; } x; x.u = ((unsigned)u) << 16; return x.f;
}
__device__ __forceinline__ unsigned short f2bf(float f) {
    union { float f; unsigned u; } x; x.f = f;
    unsigned r = x.u + 0x7fffu + ((x.u >> 16) & 1u);
    return (unsigned short)(r >> 16);
}
__device__ __forceinline__ void gload16(const void* g, void* l) {
    __builtin_amdgcn_global_load_lds(
        (const __attribute__((address_space(1))) unsigned int*)g,
        (__attribute__((address_space(3))) unsigned int*)l, 16, 0, 0);
}

// ---------------- all 4 weight casts in one dispatch ----------------
__global__ __launch_bounds__(256) void cast_w(
    const float* __restrict__ Wv, const float* __restrict__ Wqv,
    const float* __restrict__ Wq, const float* __restrict__ Wk,
    unsigned short* __restrict__ oV, unsigned short* __restrict__ oQV,
    unsigned short* __restrict__ oQ, unsigned short* __restrict__ oK)
{
    int y = blockIdx.y;
    int n = (y < 2) ? 262144 : 32768;
    const float* s = (y == 0) ? Wv : (y == 1) ? Wqv : (y == 2) ? Wq : Wk;
    unsigned short* d = (y == 0) ? oV : (y == 1) ? oQV : (y == 2) ? oQ : oK;
    int i = (blockIdx.x * 256 + threadIdx.x) * 4;
    if (i < n) {
        float4 v = *(const float4*)(s + i);
        ushort4v o = { f2bf(v.x), f2bf(v.y), f2bf(v.z), f2bf(v.w) };
        *(ushort4v*)(d + i) = o;
    }
}

// ---------------- x fp32 [C][P] -> xT bf16 [P][C], both tensors ----------------
__global__ __launch_bounds__(256) void cast_transpose_cp(
    const float* __restrict__ xq, const float* __restrict__ xe,
    unsigned short* __restrict__ xTq, unsigned short* __restrict__ xTe)
{
    int zz = blockIdx.z;
    int which = zz & 1;
    size_t b = zz >> 1;
    const float* xb = (which ? xe : xq) + b * (size_t)CP;
    unsigned short* xTb = (which ? xTe : xTq) + b * (size_t)CP;
    int p0 = blockIdx.x * 64, c0 = blockIdx.y * 64;

    __shared__ unsigned short T[64][65];
    int t = threadIdx.x;
    int pp = t & 31, cg = t >> 5;
#pragma unroll
    for (int i = 0; i < 8; ++i) {
        int c = cg + 8 * i;
        float2v v = *(const float2v*)(xb + (size_t)(c0 + c) * PP + p0 + pp * 2);
        T[c][pp * 2] = f2bf(v.x);
        T[c][pp * 2 + 1] = f2bf(v.y);
    }
    __syncthreads();
    int cp = t & 31;
#pragma unroll
    for (int i = 0; i < 8; ++i) {
        int e = t + 256 * i;
        int p = e >> 5;
        ushort2v o = { T[cp * 2][p], T[cp * 2 + 1][p] };
        *(ushort2v*)(xTb + (size_t)(p0 + p) * C_ + c0 + cp * 2) = o;
    }
}

// ---------------- MFMA GEMM q & k (BM=64, bf16 out): grid (72, 2, g) ----------------
__global__ __launch_bounds__(256) void gemm_qk(
    const unsigned short* __restrict__ Wqb, const unsigned short* __restrict__ Wkb,
    const unsigned short* __restrict__ xTq, const unsigned short* __restrict__ xTe,
    const float* __restrict__ bq, const float* __restrict__ bk,
    unsigned short* __restrict__ qout, unsigned short* __restrict__ kout)
{
    int sel = blockIdx.y;
    const unsigned short* A = sel ? Wkb : Wqb;
    const float* bias = sel ? bk : bq;
    int p0 = blockIdx.x * 128;
    size_t b = blockIdx.z;
    const unsigned short* Bb = (sel ? xTe : xTq) + b * (size_t)CP;
    unsigned short* outb = (sel ? kout : qout) + b * (size_t)C8P;

    __shared__ __align__(16) unsigned short Asm[64 * 32];
    __shared__ __align__(16) unsigned short Bsm[128 * 32];

    int tid = threadIdx.x;
    int lane = tid & 63, wid = tid >> 6;
    int wr = wid >> 1, wc = wid & 1;
    int l15 = lane & 15, l4 = lane >> 4;
    f32x4 acc[2][4] = {};

    for (int k0 = 0; k0 < 512; k0 += 32) {
        int c = tid;
        gload16(A + (size_t)(c >> 2) * 512 + k0 + (c & 3) * 8, Asm + c * 8);
        gload16(Bb + (size_t)(p0 + (c >> 2)) * 512 + k0 + (c & 3) * 8, Bsm + c * 8);
        int cb = tid + 256;
        gload16(Bb + (size_t)(p0 + (cb >> 2)) * 512 + k0 + (cb & 3) * 8, Bsm + cb * 8);
        __syncthreads();
        bf16x8 af[2], bfr[4];
#pragma unroll
        for (int m = 0; m < 2; ++m)
            af[m] = *(const bf16x8*)&Asm[(wr * 32 + m * 16 + l15) * 32 + l4 * 8];
#pragma unroll
        for (int n = 0; n < 4; ++n)
            bfr[n] = *(const bf16x8*)&Bsm[(wc * 64 + n * 16 + l15) * 32 + l4 * 8];
#pragma unroll
        for (int m = 0; m < 2; ++m)
#pragma unroll
            for (int n = 0; n < 4; ++n)
                acc[m][n] = __builtin_amdgcn_mfma_f32_16x16x32_bf16(af[m], bfr[n], acc[m][n], 0, 0, 0);
        __syncthreads();
    }
#pragma unroll
    for (int m = 0; m < 2; ++m)
#pragma unroll
        for (int n = 0; n < 4; ++n) {
            int pcol = p0 + wc * 64 + n * 16 + l15;
#pragma unroll
            for (int r = 0; r < 4; ++r) {
                int orow = wr * 32 + m * 16 + l4 * 4 + r;
                outb[(size_t)orow * PP + pcol] = f2bf(acc[m][n][r] + bias[orow]);
            }
        }
}

// ---------------- bf16 96x96 spatial transpose (q,k only) ----------------
__global__ __launch_bounds__(256) void thw_b(
    const unsigned short* __restrict__ in, unsigned short* __restrict__ out)
{
    size_t m = blockIdx.x;
    const unsigned short* im = in + m * (size_t)PP;
    unsigned short* om = out + m * (size_t)PP;
    __shared__ unsigned short T[96][97];
    int t = threadIdx.x;
#pragma unroll
    for (int i = 0; i < 18; ++i) {
        int v = t + 256 * i;
        int r = v / 48, pp = v - r * 48;
        ushort2v u = *(const ushort2v*)(im + r * 96 + pp * 2);
        T[r][pp * 2] = u.x;
        T[r][pp * 2 + 1] = u.y;
    }
    __syncthreads();
#pragma unroll
    for (int i = 0; i < 18; ++i) {
        int v = t + 256 * i;
        int w = v / 48, hh = v - w * 48;
        ushort2v o = { T[hh * 2][w], T[hh * 2 + 1][w] };
        *(ushort2v*)(om + w * 96 + hh * 2) = o;
    }
}

// ---------------- FUSED scores + exp + apply ----------------
// grid (96 s, 2 path, g), 512 thr.
// Phase A: S[m][j] = sum_c Q[c][m]*K[c][j]; e = exp(S-20) (ORI=0: diag j==m -> 0);
//          Att (LDS bf16) + row sums (ORI=0 -> rsum0 global; ORI=1 -> LDS rsl).
// Phase B (ct=0,1): stage Xs[256][104] from xT (XOR-swizzled), MFMA Att x Xs -> yT.
//          ORI=0: Y = acc (unnormalized). ORI=1: Y = (Y + acc) / (rsum0[p] + rsl[m]).
template<int ORI>
__global__ __launch_bounds__(512) void fused_sa(
    const unsigned short* __restrict__ qsrc, const unsigned short* __restrict__ ksrc,
    const unsigned short* __restrict__ xT_e, const unsigned short* __restrict__ xT_q,
    unsigned short* __restrict__ yT_e, unsigned short* __restrict__ yT_q,
    float* __restrict__ rsum0)
{
    int s = blockIdx.x;
    int path = blockIdx.y;
    size_t b = blockIdx.z;
    const unsigned short* qs = qsrc + b * (size_t)C8P;
    const unsigned short* ks = ksrc + b * (size_t)C8P;
    const unsigned short* X = (path ? xT_q : xT_e) + b * (size_t)CP;
    unsigned short* Y = (path ? yT_q : yT_e) + b * (size_t)CP;
    float* rs0 = rsum0 + b * (size_t)PP;

    // union region: phase A = Qs/Ks fp32 [64][97] each (49.7 KB); phase B = Xs u16 [256][104] (53.2 KB)
    __shared__ __align__(16) char U[53248];
    float* Qs = (float*)U;
    float* Ks = Qs + 64 * 97;
    unsigned short* Xs = (unsigned short*)U;
    __shared__ __align__(16) unsigned short Att[96][104];
    __shared__ float rsl[96];

    int t = threadIdx.x;
    int lane = t & 63, wid = t >> 6;

    // ---- phase A: stage q,k (bf16 -> fp32 LDS) ----
    for (int v = t; v < 64 * 12; v += 512) {
        int c = v / 12, gg = v - c * 12;
        size_t gi = (size_t)c * PP + (size_t)s * 96 + gg * 8;
        ushort8 uq = *(const ushort8*)(qs + gi);
        ushort8 uk = *(const ushort8*)(ks + gi);
#pragma unroll
        for (int e = 0; e < 8; ++e) {
            Qs[c * 97 + gg * 8 + e] = bf2f(uq[e]);
            Ks[c * 97 + gg * 8 + e] = bf2f(uk[e]);
        }
    }
    __syncthreads();

    int tx = t & 15, ty = t >> 4;    // ty 0..31
    float acc[3][6] = {};
    for (int c = 0; c < 64; ++c) {
        float qf[3], kf[6];
#pragma unroll
        for (int i = 0; i < 3; ++i) qf[i] = Qs[c * 97 + ty + 32 * i];
#pragma unroll
        for (int j = 0; j < 6; ++j) kf[j] = Ks[c * 97 + tx + 16 * j];
#pragma unroll
        for (int i = 0; i < 3; ++i)
#pragma unroll
            for (int j = 0; j < 6; ++j) acc[i][j] = fmaf(qf[i], kf[j], acc[i][j]);
    }
#pragma unroll
    for (int i = 0; i < 3; ++i) {
        int m = ty + 32 * i;
        float part = 0.0f;
#pragma unroll
        for (int j = 0; j < 6; ++j) {
            int jj = tx + 16 * j;
            float e = (ORI == 0 && jj == m) ? 0.0f : __expf(acc[i][j] - 20.0f);
            part += e;
            Att[m][jj] = f2bf(e);
        }
#pragma unroll
        for (int off = 1; off < 16; off <<= 1) part += __shfl_xor(part, off);
        if (tx == 0) {
            if (ORI == 0) rs0[(size_t)m * 96 + s] = part;
            else          rsl[m] = part;
        }
    }
    __syncthreads();   // Att + rsl ready; Qs/Ks dead

    // ---- phase B: two c-tiles ----
    int wm = wid >> 2, wn = wid & 3;
    int l15 = lane & 15, l4 = lane >> 4;
#pragma unroll
    for (int ct = 0; ct < 2; ++ct) {
        int c0 = ct * 256;
        for (int v = t; v < 96 * 32; v += 512) {
            int j = v >> 5, cc = v & 31;
            size_t pj = ORI ? ((size_t)s * 96 + j) : ((size_t)j * 96 + s);
            ushort8 u = *(const ushort8*)(X + pj * C_ + c0 + cc * 8);
            int js = j ^ ((cc & 3) << 3);
#pragma unroll
            for (int e = 0; e < 8; ++e) Xs[(cc * 8 + e) * 104 + js] = u[e];
        }
        __syncthreads();

        f32x4 pacc[3][4] = {};
#pragma unroll
        for (int k = 0; k < 3; ++k) {
            bf16x8 a[3], xx[4];
#pragma unroll
            for (int mi = 0; mi < 3; ++mi)
                a[mi] = *(const bf16x8*)&Att[wm * 48 + mi * 16 + l15][k * 32 + l4 * 8];
#pragma unroll
            for (int ni = 0; ni < 4; ++ni) {
                int row = wn * 64 + ni * 16 + l15;
                int gsw = (k * 4 + l4) ^ ((row >> 3) & 3);
                xx[ni] = *(const bf16x8*)&Xs[row * 104 + gsw * 8];
            }
#pragma unroll
            for (int mi = 0; mi < 3; ++mi)
#pragma unroll
                for (int ni = 0; ni < 4; ++ni)
                    pacc[mi][ni] = __builtin_amdgcn_mfma_f32_16x16x32_bf16(a[mi], xx[ni], pacc[mi][ni], 0, 0, 0);
        }

#pragma unroll
        for (int mi = 0; mi < 3; ++mi) {
#pragma unroll
            for (int r = 0; r < 4; ++r) {
                int mrow = wm * 48 + mi * 16 + l4 * 4 + r;
                size_t p = ORI ? ((size_t)s * 96 + mrow) : ((size_t)mrow * 96 + s);
                float rinv = 0.0f;
                if (ORI) rinv = 1.0f / (rs0[p] + rsl[mrow]);
                size_t base = p * C_ + c0;
#pragma unroll
                for (int ni = 0; ni < 4; ++ni) {
                    size_t idx = base + wn * 64 + ni * 16 + l15;
                    if (ORI == 0) {
                        Y[idx] = f2bf(pacc[mi][ni][r]);
                    } else {
                        float tot = bf2f(Y[idx]) + pacc[mi][ni][r];
                        Y[idx] = f2bf(tot * rinv);
                    }
                }
            }
        }
        __syncthreads();   // all Xs reads done before restage / exit
    }
}

// ---------------- final GEMM + fused epilogue, BK=64, XOR swizzle, 2-phase dbuf ----------------
__global__ __launch_bounds__(256) void gemm_out(
    const unsigned short* __restrict__ Wvb, const unsigned short* __restrict__ Wqvb,
    const unsigned short* __restrict__ yT_e, const unsigned short* __restrict__ yT_q,
    const float* __restrict__ bv, const float* __restrict__ bqv,
    const float* __restrict__ xe, const float* __restrict__ xq,
    const float* __restrict__ g1, const float* __restrict__ g2,
    float* __restrict__ o0, float* __restrict__ o1)
{
    int yy = blockIdx.y;
    int path = yy >> 2, ot = yy & 3;
    const unsigned short* A = path ? Wqvb : Wvb;
    const float* bias = path ? bqv : bv;
    int p0 = blockIdx.x * 128;
    int o0r = ot * 128;
    size_t b = blockIdx.z;
    const unsigned short* Bb = (path ? yT_q : yT_e) + b * (size_t)CP;
    const float* xb = (path ? xq : xe) + b * (size_t)CP;
    float* ob = (path ? o1 : o0) + b * (size_t)CP;
    float gam = (path ? g2 : g1)[0];

    __shared__ __align__(16) unsigned short Asm[2][128 * 64];
    __shared__ __align__(16) unsigned short Bsm[2][128 * 64];

    int tid = threadIdx.x;
    int lane = tid & 63, wid = tid >> 6;
    int wr = wid >> 1, wc = wid & 1;
    int l15 = lane & 15, l4 = lane >> 4;
    f32x4 acc[4][4] = {};

#pragma unroll
    for (int i = 0; i < 4; ++i) {
        int ch = tid + i * 256;
        int row = ch >> 3, slot = ch & 7;
        int gs = slot ^ (row & 7);
        gload16(A + (size_t)(o0r + row) * 512 + gs * 8, Asm[0] + ch * 8);
        gload16(Bb + (size_t)(p0 + row) * 512 + gs * 8, Bsm[0] + ch * 8);
    }
    __syncthreads();

#pragma unroll
    for (int k = 0; k < 8; ++k) {
        int cur = k & 1;
        if (k < 7) {
            int k0n = (k + 1) * 64;
            int nxt = cur ^ 1;
#pragma unroll
            for (int i = 0; i < 4; ++i) {
                int ch = tid + i * 256;
                int row = ch >> 3, slot = ch & 7;
                int gs = slot ^ (row & 7);
                gload16(A + (size_t)(o0r + row) * 512 + k0n + gs * 8, Asm[nxt] + ch * 8);
                gload16(Bb + (size_t)(p0 + row) * 512 + k0n + gs * 8, Bsm[nxt] + ch * 8);
            }
        }
#pragma unroll
        for (int ks = 0; ks < 2; ++ks) {
            bf16x8 af[4], bfr[4];
#pragma unroll
            for (int m = 0; m < 4; ++m) {
                int row = wr * 64 + m * 16 + l15;
                int sl = (ks * 4 + l4) ^ (row & 7);
                af[m] = *(const bf16x8*)&Asm[cur][row * 64 + sl * 8];
            }
#pragma unroll
            for (int n = 0; n < 4; ++n) {
                int row = wc * 64 + n * 16 + l15;
                int sl = (ks * 4 + l4) ^ (row & 7);
                bfr[n] = *(const bf16x8*)&Bsm[cur][row * 64 + sl * 8];
            }
#pragma unroll
            for (int m = 0; m < 4; ++m)
#pragma unroll
                for (int n = 0; n < 4; ++n)
                    acc[m][n] = __builtin_amdgcn_mfma_f32_16x16x32_bf16(af[m], bfr[n], acc[m][n], 0, 0, 0);
        }
        __syncthreads();
    }

#pragma unroll
    for (int m = 0; m < 4; ++m)
#pragma unroll
        for (int n = 0; n < 4; ++n) {
            int pcol = p0 + wc * 64 + n * 16 + l15;
#pragma unroll
            for (int r = 0; r < 4; ++r) {
                int orow = o0r + wr * 64 + m * 16 + l4 * 4 + r;
                size_t idx = (size_t)orow * PP + pcol;
                float val = acc[m][n][r] + bias[orow];
                ob[idx] = gam * (val + 2.0f) + xb[idx];
            }
        }
}

extern "C" void kernel_launch(void* const* d_in, const int* in_sizes, int n_in,
                              void* d_out, int out_size, void* d_ws, size_t ws_size,
                              hipStream_t stream)
{
    const float* x_ex = (const float*)d_in[0];
    const float* x_q  = (const float*)d_in[1];
    const float* Wq   = (const float*)d_in[2];
    const float* bq   = (const float*)d_in[3];
    const float* Wk   = (const float*)d_in[4];
    const float* bk   = (const float*)d_in[5];
    const float* Wv   = (const float*)d_in[6];
    const float* bv   = (const float*)d_in[7];
    const float* Wqv  = (const float*)d_in[8];
    const float* bqv  = (const float*)d_in[9];
    const float* g1   = (const float*)d_in[10];
    const float* g2   = (const float*)d_in[11];
    float* out0 = (float*)d_out;
    float* out1 = out0 + (size_t)8 * CP;

    unsigned short* hp = (unsigned short*)d_ws;
    unsigned short* Wvb  = hp; hp += 262144;
    unsigned short* Wqvb = hp; hp += 262144;
    unsigned short* Wqb  = hp; hp += 32768;
    unsigned short* Wkb  = hp; hp += 32768;
    size_t head = (size_t)(hp - (unsigned short*)d_ws) * 2;

    size_t perB = 4ull * CP + 4ull * C8P + 2ull * PP;   // u16 units (rsum0 fp32 = 2 u16 each)
    int g = 8;
    while (g > 1 && head + (size_t)g * perB * 2 > ws_size) g >>= 1;

    unsigned short* p = hp;
    unsigned short* xT_e = p; p += (size_t)g * CP;
    unsigned short* xT_q = p; p += (size_t)g * CP;
    unsigned short* yT_e = p; p += (size_t)g * CP;
    unsigned short* yT_q = p; p += (size_t)g * CP;
    unsigned short* qb   = p; p += (size_t)g * C8P;
    unsigned short* kb   = p; p += (size_t)g * C8P;  // adjacent to qb
    unsigned short* qTb  = p; p += (size_t)g * C8P;
    unsigned short* kTb  = p; p += (size_t)g * C8P;  // adjacent to qTb
    float* rsum0 = (float*)p; p += (size_t)g * PP * 2;

    cast_w<<<dim3(256, 4), 256, 0, stream>>>(Wv, Wqv, Wq, Wk, Wvb, Wqvb, Wqb, Wkb);

    for (int b0 = 0; b0 < 8; b0 += g) {
        const float* xe = x_ex + (size_t)b0 * CP;
        const float* xq = x_q  + (size_t)b0 * CP;
        float* o0 = out0 + (size_t)b0 * CP;
        float* o1 = out1 + (size_t)b0 * CP;

        cast_transpose_cp<<<dim3(144, 8, 2 * g), 256, 0, stream>>>(xq, xe, xT_q, xT_e);
        gemm_qk<<<dim3(72, 2, g), 256, 0, stream>>>(Wqb, Wkb, xT_q, xT_e, bq, bk, qb, kb);
        thw_b<<<dim3(2 * g * 64), 256, 0, stream>>>(qb, qTb);   // qb,kb -> qTb,kTb
        fused_sa<0><<<dim3(96, 2, g), 512, 0, stream>>>(qTb, kTb, xT_e, xT_q, yT_e, yT_q, rsum0);
        fused_sa<1><<<dim3(96, 2, g), 512, 0, stream>>>(qb,  kb,  xT_e, xT_q, yT_e, yT_q, rsum0);
        gemm_out<<<dim3(72, 8, g), 256, 0, stream>>>(Wvb, Wqvb, yT_e, yT_q, bv, bqv,
                                                     xe, xq, g1, g2, o0, o1);
    }
}

// Round 11
// 583.639 us; speedup vs baseline: 1.1060x; 1.1060x over previous
//
#include <hip/hip_runtime.h>
#include <math.h>

#define C_   512
#define C8_  64
#define HH   96
#define WW   96
#define PP   9216            // HH*WW
#define CP   4718592         // C_*PP
#define C8P  589824          // C8_*PP
#define ATTN 1769472         // PP*192

typedef __attribute__((ext_vector_type(4))) float f32x4;
typedef __attribute__((ext_vector_type(8))) __bf16 bf16x8;
typedef __attribute__((ext_vector_type(8))) unsigned short ushort8;
typedef __attribute__((ext_vector_type(4))) unsigned short ushort4v;
typedef __attribute__((ext_vector_type(2))) unsigned short ushort2v;
typedef __attribute__((ext_vector_type(2))) float float2v;

__device__ __forceinline__ float bf2f(unsigned short u) {
    union { unsigned u; float f; } x; x.u = ((unsigned)u) << 16; return x.f;
}
__device__ __forceinline__ unsigned short f2bf(float f) {
    union { float f; unsigned u; } x; x.f = f;
    unsigned r = x.u + 0x7fffu + ((x.u >> 16) & 1u);
    return (unsigned short)(r >> 16);
}
__device__ __forceinline__ void gload16(const void* g, void* l) {
    __builtin_amdgcn_global_load_lds(
        (const __attribute__((address_space(1))) unsigned int*)g,
        (__attribute__((address_space(3))) unsigned int*)l, 16, 0, 0);
}

// ---------------- all 4 weight casts in one dispatch ----------------
__global__ __launch_bounds__(256) void cast_w(
    const float* __restrict__ Wv, const float* __restrict__ Wqv,
    const float* __restrict__ Wq, const float* __restrict__ Wk,
    unsigned short* __restrict__ oV, unsigned short* __restrict__ oQV,
    unsigned short* __restrict__ oQ, unsigned short* __restrict__ oK)
{
    int y = blockIdx.y;
    int n = (y < 2) ? 262144 : 32768;
    const float* s = (y == 0) ? Wv : (y == 1) ? Wqv : (y == 2) ? Wq : Wk;
    unsigned short* d = (y == 0) ? oV : (y == 1) ? oQV : (y == 2) ? oQ : oK;
    int i = (blockIdx.x * 256 + threadIdx.x) * 4;
    if (i < n) {
        float4 v = *(const float4*)(s + i);
        ushort4v o = { f2bf(v.x), f2bf(v.y), f2bf(v.z), f2bf(v.w) };
        *(ushort4v*)(d + i) = o;
    }
}

// ---------------- x fp32 [C][P] -> xT bf16 [P][C], both tensors ----------------
__global__ __launch_bounds__(256) void cast_transpose_cp(
    const float* __restrict__ xq, const float* __restrict__ xe,
    unsigned short* __restrict__ xTq, unsigned short* __restrict__ xTe)
{
    int zz = blockIdx.z;
    int which = zz & 1;
    size_t b = zz >> 1;
    const float* xb = (which ? xe : xq) + b * (size_t)CP;
    unsigned short* xTb = (which ? xTe : xTq) + b * (size_t)CP;
    int p0 = blockIdx.x * 64, c0 = blockIdx.y * 64;

    __shared__ unsigned short T[64][65];
    int t = threadIdx.x;
    int pp = t & 31, cg = t >> 5;
#pragma unroll
    for (int i = 0; i < 8; ++i) {
        int c = cg + 8 * i;
        float2v v = *(const float2v*)(xb + (size_t)(c0 + c) * PP + p0 + pp * 2);
        T[c][pp * 2] = f2bf(v.x);
        T[c][pp * 2 + 1] = f2bf(v.y);
    }
    __syncthreads();
    int cp = t & 31;
#pragma unroll
    for (int i = 0; i < 8; ++i) {
        int e = t + 256 * i;
        int p = e >> 5;
        ushort2v o = { T[cp * 2][p], T[cp * 2 + 1][p] };
        *(ushort2v*)(xTb + (size_t)(p0 + p) * C_ + c0 + cp * 2) = o;
    }
}

// ---------------- MFMA GEMM q & k (BM=64, bf16 out): grid (72, 2, g) ----------------
__global__ __launch_bounds__(256) void gemm_qk(
    const unsigned short* __restrict__ Wqb, const unsigned short* __restrict__ Wkb,
    const unsigned short* __restrict__ xTq, const unsigned short* __restrict__ xTe,
    const float* __restrict__ bq, const float* __restrict__ bk,
    unsigned short* __restrict__ qout, unsigned short* __restrict__ kout)
{
    int sel = blockIdx.y;
    const unsigned short* A = sel ? Wkb : Wqb;
    const float* bias = sel ? bk : bq;
    int p0 = blockIdx.x * 128;
    size_t b = blockIdx.z;
    const unsigned short* Bb = (sel ? xTe : xTq) + b * (size_t)CP;
    unsigned short* outb = (sel ? kout : qout) + b * (size_t)C8P;

    __shared__ __align__(16) unsigned short Asm[64 * 32];
    __shared__ __align__(16) unsigned short Bsm[128 * 32];

    int tid = threadIdx.x;
    int lane = tid & 63, wid = tid >> 6;
    int wr = wid >> 1, wc = wid & 1;
    int l15 = lane & 15, l4 = lane >> 4;
    f32x4 acc[2][4] = {};

    for (int k0 = 0; k0 < 512; k0 += 32) {
        int c = tid;
        gload16(A + (size_t)(c >> 2) * 512 + k0 + (c & 3) * 8, Asm + c * 8);
        gload16(Bb + (size_t)(p0 + (c >> 2)) * 512 + k0 + (c & 3) * 8, Bsm + c * 8);
        int cb = tid + 256;
        gload16(Bb + (size_t)(p0 + (cb >> 2)) * 512 + k0 + (cb & 3) * 8, Bsm + cb * 8);
        __syncthreads();
        bf16x8 af[2], bfr[4];
#pragma unroll
        for (int m = 0; m < 2; ++m)
            af[m] = *(const bf16x8*)&Asm[(wr * 32 + m * 16 + l15) * 32 + l4 * 8];
#pragma unroll
        for (int n = 0; n < 4; ++n)
            bfr[n] = *(const bf16x8*)&Bsm[(wc * 64 + n * 16 + l15) * 32 + l4 * 8];
#pragma unroll
        for (int m = 0; m < 2; ++m)
#pragma unroll
            for (int n = 0; n < 4; ++n)
                acc[m][n] = __builtin_amdgcn_mfma_f32_16x16x32_bf16(af[m], bfr[n], acc[m][n], 0, 0, 0);
        __syncthreads();
    }
#pragma unroll
    for (int m = 0; m < 2; ++m)
#pragma unroll
        for (int n = 0; n < 4; ++n) {
            int pcol = p0 + wc * 64 + n * 16 + l15;
#pragma unroll
            for (int r = 0; r < 4; ++r) {
                int orow = wr * 32 + m * 16 + l4 * 4 + r;
                outb[(size_t)orow * PP + pcol] = f2bf(acc[m][n][r] + bias[orow]);
            }
        }
}

// ---------------- bf16 96x96 spatial transpose (q,k only) ----------------
__global__ __launch_bounds__(256) void thw_b(
    const unsigned short* __restrict__ in, unsigned short* __restrict__ out)
{
    size_t m = blockIdx.x;
    const unsigned short* im = in + m * (size_t)PP;
    unsigned short* om = out + m * (size_t)PP;
    __shared__ unsigned short T[96][97];
    int t = threadIdx.x;
#pragma unroll
    for (int i = 0; i < 18; ++i) {
        int v = t + 256 * i;
        int r = v / 48, pp = v - r * 48;
        ushort2v u = *(const ushort2v*)(im + r * 96 + pp * 2);
        T[r][pp * 2] = u.x;
        T[r][pp * 2 + 1] = u.y;
    }
    __syncthreads();
#pragma unroll
    for (int i = 0; i < 18; ++i) {
        int v = t + 256 * i;
        int w = v / 48, hh = v - w * 48;
        ushort2v o = { T[hh * 2][w], T[hh * 2 + 1][w] };
        *(ushort2v*)(om + w * 96 + hh * 2) = o;
    }
}

// ---------------- scores + exp + row-partial-sums: grid (96, 2, g) ----------------
__global__ __launch_bounds__(256) void scores_kernel(
    const unsigned short* __restrict__ qT, const unsigned short* __restrict__ kT,
    const unsigned short* __restrict__ q, const unsigned short* __restrict__ k,
    unsigned short* __restrict__ attb, float* __restrict__ rsum0, float* __restrict__ rsum1)
{
    int s = blockIdx.x;
    int ori = blockIdx.y;
    size_t b = blockIdx.z;
    const unsigned short* qs = (ori ? q : qT) + b * (size_t)C8P;
    const unsigned short* ks = (ori ? k : kT) + b * (size_t)C8P;
    unsigned short* ab = attb + b * (size_t)ATTN;
    float* rs = (ori ? rsum1 : rsum0) + b * (size_t)PP;

    __shared__ float Qs[64][97];
    __shared__ float Ks[64][97];
    int t = threadIdx.x;
    for (int v = t; v < 64 * 12; v += 256) {
        int c = v / 12, gg = v - c * 12;
        size_t gi = (size_t)c * PP + (size_t)s * 96 + gg * 8;
        ushort8 uq = *(const ushort8*)(qs + gi);
        ushort8 uk = *(const ushort8*)(ks + gi);
#pragma unroll
        for (int kk = 0; kk < 8; ++kk) {
            Qs[c][gg * 8 + kk] = bf2f(uq[kk]);
            Ks[c][gg * 8 + kk] = bf2f(uk[kk]);
        }
    }
    __syncthreads();
    int tx = t & 15, ty = t >> 4;
    float acc[6][6] = {};
    for (int c = 0; c < 64; ++c) {
        float qf[6], kf[6];
#pragma unroll
        for (int i = 0; i < 6; ++i) { qf[i] = Qs[c][ty + 16 * i]; kf[i] = Ks[c][tx + 16 * i]; }
#pragma unroll
        for (int i = 0; i < 6; ++i)
#pragma unroll
            for (int j = 0; j < 6; ++j) acc[i][j] = fmaf(qf[i], kf[j], acc[i][j]);
    }
#pragma unroll
    for (int i = 0; i < 6; ++i) {
        int m = ty + 16 * i;
        size_t row = ori ? ((size_t)s * 96 + m) : ((size_t)m * 96 + s);
        unsigned short* rowp = ab + row * 192 + (ori ? 96 : 0);
        float part = 0.0f;
#pragma unroll
        for (int j = 0; j < 6; ++j) {
            int jj = tx + 16 * j;
            float e = (!ori && jj == m) ? 0.0f : __expf(acc[i][j] - 20.0f);
            part += e;
            rowp[jj] = f2bf(e);
        }
#pragma unroll
        for (int off = 1; off < 16; off <<= 1) part += __shfl_xor(part, off);
        if (tx == 0) rs[row] = part;
    }
}

// ---------------- MFMA apply on x (staged from xT, XOR-swizzled): yT[p][c] ----------------
// grid (96 s, 4 = path*2+ct, g), 512 thr = 8 waves (2 m x 4 n)
template<int ORI>
__global__ __launch_bounds__(512) void apply_mfma(
    const unsigned short* __restrict__ xT_e, const unsigned short* __restrict__ xT_q,
    unsigned short* __restrict__ yT_e, unsigned short* __restrict__ yT_q,
    const unsigned short* __restrict__ attb,
    const float* __restrict__ rsum0, const float* __restrict__ rsum1)
{
    int s = blockIdx.x;
    int path = blockIdx.y >> 1, ct = blockIdx.y & 1;
    int c0 = ct * 256;
    size_t b = blockIdx.z;
    const unsigned short* X = (path ? xT_q : xT_e) + b * (size_t)CP;
    unsigned short* Y = (path ? yT_q : yT_e) + b * (size_t)CP;
    const unsigned short* ab = attb + b * (size_t)ATTN;
    const float* r0 = rsum0 + b * (size_t)PP;
    const float* r1 = rsum1 + b * (size_t)PP;

    __shared__ __align__(16) unsigned short Att[96][104];
    __shared__ __align__(16) unsigned short Xs[256][104];   // [c][j], col-group XOR-swizzled by (c>>3)&3

    int tid = threadIdx.x;
    for (int v = tid; v < 96 * 12; v += 512) {
        int r = v / 12, gg = v - r * 12;
        size_t base = ORI ? ((size_t)(s * 96 + r) * 192 + 96) : ((size_t)(r * 96 + s) * 192);
        *(ushort8*)&Att[r][gg * 8] = *(const ushort8*)(ab + base + gg * 8);
    }
    for (int v = tid; v < 96 * 32; v += 512) {
        int j = v >> 5, cc = v & 31;
        size_t pj = ORI ? ((size_t)s * 96 + j) : ((size_t)j * 96 + s);
        ushort8 u = *(const ushort8*)(X + pj * C_ + c0 + cc * 8);
        int js = j ^ ((cc & 3) << 3);
#pragma unroll
        for (int e = 0; e < 8; ++e) Xs[cc * 8 + e][js] = u[e];
    }
    __syncthreads();

    int lane = tid & 63, wid = tid >> 6;
    int wm = wid >> 2, wn = wid & 3;
    int l15 = lane & 15, l4 = lane >> 4;
    f32x4 acc[3][4] = {};
#pragma unroll
    for (int k = 0; k < 3; ++k) {
        bf16x8 a[3], xx[4];
#pragma unroll
        for (int mi = 0; mi < 3; ++mi)
            a[mi] = *(const bf16x8*)&Att[wm * 48 + mi * 16 + l15][k * 32 + l4 * 8];
#pragma unroll
        for (int ni = 0; ni < 4; ++ni) {
            int row = wn * 64 + ni * 16 + l15;
            int gsw = (k * 4 + l4) ^ ((row >> 3) & 3);
            xx[ni] = *(const bf16x8*)&Xs[row][gsw * 8];
        }
#pragma unroll
        for (int mi = 0; mi < 3; ++mi)
#pragma unroll
            for (int ni = 0; ni < 4; ++ni)
                acc[mi][ni] = __builtin_amdgcn_mfma_f32_16x16x32_bf16(a[mi], xx[ni], acc[mi][ni], 0, 0, 0);
    }

#pragma unroll
    for (int mi = 0; mi < 3; ++mi) {
#pragma unroll
        for (int r = 0; r < 4; ++r) {
            int mrow = wm * 48 + mi * 16 + l4 * 4 + r;
            size_t p = ORI ? ((size_t)s * 96 + mrow) : ((size_t)mrow * 96 + s);
            float rinv = 0.0f;
            if (ORI) rinv = 1.0f / (r0[p] + r1[p]);
            size_t base = p * C_ + c0;
#pragma unroll
            for (int ni = 0; ni < 4; ++ni) {
                size_t idx = base + wn * 64 + ni * 16 + l15;
                if (ORI == 0) {
                    Y[idx] = f2bf(acc[mi][ni][r]);
                } else {
                    float tot = bf2f(Y[idx]) + acc[mi][ni][r];
                    Y[idx] = f2bf(tot * rinv);
                }
            }
        }
    }
}

// ---------------- final GEMM + fused epilogue: 512 thr / 8 waves, BK=64, swizzle, dbuf ----------------
// grid (72, 8, g); y = path*4 + ot; out = gam*(W.yT + bias + 2) + x
__global__ __launch_bounds__(512) void gemm_out(
    const unsigned short* __restrict__ Wvb, const unsigned short* __restrict__ Wqvb,
    const unsigned short* __restrict__ yT_e, const unsigned short* __restrict__ yT_q,
    const float* __restrict__ bv, const float* __restrict__ bqv,
    const float* __restrict__ xe, const float* __restrict__ xq,
    const float* __restrict__ g1, const float* __restrict__ g2,
    float* __restrict__ o0, float* __restrict__ o1)
{
    int yy = blockIdx.y;
    int path = yy >> 2, ot = yy & 3;
    const unsigned short* A = path ? Wqvb : Wvb;
    const float* bias = path ? bqv : bv;
    int p0 = blockIdx.x * 128;
    int o0r = ot * 128;
    size_t b = blockIdx.z;
    const unsigned short* Bb = (path ? yT_q : yT_e) + b * (size_t)CP;
    const float* xb = (path ? xq : xe) + b * (size_t)CP;
    float* ob = (path ? o1 : o0) + b * (size_t)CP;
    float gam = (path ? g2 : g1)[0];

    __shared__ __align__(16) unsigned short Asm[2][128 * 64];
    __shared__ __align__(16) unsigned short Bsm[2][128 * 64];

    int tid = threadIdx.x;             // 0..511, 8 waves
    int lane = tid & 63, wid = tid >> 6;
    int wr = wid >> 2, wc = wid & 3;   // 2 x 4 wave grid; wave tile 64 rows x 32 cols
    int l15 = lane & 15, l4 = lane >> 4;
    f32x4 acc[4][2] = {};

    // prologue: stage tile 0 into buf 0 (1024 A-chunks + 1024 B-chunks over 512 thr)
#pragma unroll
    for (int i = 0; i < 2; ++i) {
        int ch = tid + i * 512;
        int row = ch >> 3, slot = ch & 7;
        int gs = slot ^ (row & 7);
        gload16(A + (size_t)(o0r + row) * 512 + gs * 8, Asm[0] + ch * 8);
        gload16(Bb + (size_t)(p0 + row) * 512 + gs * 8, Bsm[0] + ch * 8);
    }
    __syncthreads();

#pragma unroll
    for (int k = 0; k < 8; ++k) {
        int cur = k & 1;
        if (k < 7) {
            int k0n = (k + 1) * 64;
            int nxt = cur ^ 1;
#pragma unroll
            for (int i = 0; i < 2; ++i) {
                int ch = tid + i * 512;
                int row = ch >> 3, slot = ch & 7;
                int gs = slot ^ (row & 7);
                gload16(A + (size_t)(o0r + row) * 512 + k0n + gs * 8, Asm[nxt] + ch * 8);
                gload16(Bb + (size_t)(p0 + row) * 512 + k0n + gs * 8, Bsm[nxt] + ch * 8);
            }
        }
#pragma unroll
        for (int ks = 0; ks < 2; ++ks) {
            bf16x8 af[4], bfr[2];
#pragma unroll
            for (int m = 0; m < 4; ++m) {
                int row = wr * 64 + m * 16 + l15;
                int sl = (ks * 4 + l4) ^ (row & 7);
                af[m] = *(const bf16x8*)&Asm[cur][row * 64 + sl * 8];
            }
#pragma unroll
            for (int n = 0; n < 2; ++n) {
                int row = wc * 32 + n * 16 + l15;
                int sl = (ks * 4 + l4) ^ (row & 7);
                bfr[n] = *(const bf16x8*)&Bsm[cur][row * 64 + sl * 8];
            }
#pragma unroll
            for (int m = 0; m < 4; ++m)
#pragma unroll
                for (int n = 0; n < 2; ++n)
                    acc[m][n] = __builtin_amdgcn_mfma_f32_16x16x32_bf16(af[m], bfr[n], acc[m][n], 0, 0, 0);
        }
        __syncthreads();
    }

#pragma unroll
    for (int m = 0; m < 4; ++m)
#pragma unroll
        for (int n = 0; n < 2; ++n) {
            int pcol = p0 + wc * 32 + n * 16 + l15;
#pragma unroll
            for (int r = 0; r < 4; ++r) {
                int orow = o0r + wr * 64 + m * 16 + l4 * 4 + r;
                size_t idx = (size_t)orow * PP + pcol;
                float val = acc[m][n][r] + bias[orow];
                ob[idx] = gam * (val + 2.0f) + xb[idx];
            }
        }
}

extern "C" void kernel_launch(void* const* d_in, const int* in_sizes, int n_in,
                              void* d_out, int out_size, void* d_ws, size_t ws_size,
                              hipStream_t stream)
{
    const float* x_ex = (const float*)d_in[0];
    const float* x_q  = (const float*)d_in[1];
    const float* Wq   = (const float*)d_in[2];
    const float* bq   = (const float*)d_in[3];
    const float* Wk   = (const float*)d_in[4];
    const float* bk   = (const float*)d_in[5];
    const float* Wv   = (const float*)d_in[6];
    const float* bv   = (const float*)d_in[7];
    const float* Wqv  = (const float*)d_in[8];
    const float* bqv  = (const float*)d_in[9];
    const float* g1   = (const float*)d_in[10];
    const float* g2   = (const float*)d_in[11];
    float* out0 = (float*)d_out;
    float* out1 = out0 + (size_t)8 * CP;

    unsigned short* hp = (unsigned short*)d_ws;
    unsigned short* Wvb  = hp; hp += 262144;
    unsigned short* Wqvb = hp; hp += 262144;
    unsigned short* Wqb  = hp; hp += 32768;
    unsigned short* Wkb  = hp; hp += 32768;
    size_t head = (size_t)(hp - (unsigned short*)d_ws) * 2;

    size_t perB = 4ull * CP + (size_t)ATTN + 4ull * C8P + 4ull * PP;
    int g = 8;
    while (g > 1 && head + (size_t)g * perB * 2 > ws_size) g >>= 1;

    unsigned short* p = hp;
    unsigned short* xT_e = p; p += (size_t)g * CP;
    unsigned short* xT_q = p; p += (size_t)g * CP;
    unsigned short* yT_e = p; p += (size_t)g * CP;
    unsigned short* yT_q = p; p += (size_t)g * CP;
    unsigned short* attb = p; p += (size_t)g * ATTN;
    unsigned short* qb   = p; p += (size_t)g * C8P;
    unsigned short* kb   = p; p += (size_t)g * C8P;  // adjacent to qb
    unsigned short* qTb  = p; p += (size_t)g * C8P;
    unsigned short* kTb  = p; p += (size_t)g * C8P;  // adjacent to qTb
    float* rsum0 = (float*)p; p += (size_t)g * PP * 2;
    float* rsum1 = (float*)p; p += (size_t)g * PP * 2;

    cast_w<<<dim3(256, 4), 256, 0, stream>>>(Wv, Wqv, Wq, Wk, Wvb, Wqvb, Wqb, Wkb);

    for (int b0 = 0; b0 < 8; b0 += g) {
        const float* xe = x_ex + (size_t)b0 * CP;
        const float* xq = x_q  + (size_t)b0 * CP;
        float* o0 = out0 + (size_t)b0 * CP;
        float* o1 = out1 + (size_t)b0 * CP;

        cast_transpose_cp<<<dim3(144, 8, 2 * g), 256, 0, stream>>>(xq, xe, xT_q, xT_e);
        gemm_qk<<<dim3(72, 2, g), 256, 0, stream>>>(Wqb, Wkb, xT_q, xT_e, bq, bk, qb, kb);
        thw_b<<<dim3(2 * g * 64), 256, 0, stream>>>(qb, qTb);
        scores_kernel<<<dim3(96, 2, g), 256, 0, stream>>>(qTb, kTb, qb, kb, attb, rsum0, rsum1);
        apply_mfma<0><<<dim3(96, 4, g), 512, 0, stream>>>(xT_e, xT_q, yT_e, yT_q, attb, rsum0, rsum1);
        apply_mfma<1><<<dim3(96, 4, g), 512, 0, stream>>>(xT_e, xT_q, yT_e, yT_q, attb, rsum0, rsum1);
        gemm_out<<<dim3(72, 8, g), 512, 0, stream>>>(Wvb, Wqvb, yT_e, yT_q, bv, bqv,
                                                     xe, xq, g1, g2, o0, o1);
    }
}

// Round 12
// 573.867 us; speedup vs baseline: 1.1249x; 1.0170x over previous
//
#include <hip/hip_runtime.h>
#include <math.h>

#define C_   512
#define C8_  64
#define HH   96
#define WW   96
#define PP   9216            // HH*WW
#define CP   4718592         // C_*PP
#define C8P  589824          // C8_*PP
#define ATTN 1769472         // PP*192

typedef __attribute__((ext_vector_type(4))) float f32x4;
typedef __attribute__((ext_vector_type(8))) __bf16 bf16x8;
typedef __attribute__((ext_vector_type(8))) unsigned short ushort8;
typedef __attribute__((ext_vector_type(4))) unsigned short ushort4v;
typedef __attribute__((ext_vector_type(2))) unsigned short ushort2v;
typedef __attribute__((ext_vector_type(2))) float float2v;

__device__ __forceinline__ float bf2f(unsigned short u) {
    union { unsigned u; float f; } x; x.u = ((unsigned)u) << 16; return x.f;
}
__device__ __forceinline__ unsigned short f2bf(float f) {
    union { float f; unsigned u; } x; x.f = f;
    unsigned r = x.u + 0x7fffu + ((x.u >> 16) & 1u);
    return (unsigned short)(r >> 16);
}
__device__ __forceinline__ void gload16(const void* g, void* l) {
    __builtin_amdgcn_global_load_lds(
        (const __attribute__((address_space(1))) unsigned int*)g,
        (__attribute__((address_space(3))) unsigned int*)l, 16, 0, 0);
}

// ---------------- all 4 weight casts in one dispatch ----------------
__global__ __launch_bounds__(256) void cast_w(
    const float* __restrict__ Wv, const float* __restrict__ Wqv,
    const float* __restrict__ Wq, const float* __restrict__ Wk,
    unsigned short* __restrict__ oV, unsigned short* __restrict__ oQV,
    unsigned short* __restrict__ oQ, unsigned short* __restrict__ oK)
{
    int y = blockIdx.y;
    int n = (y < 2) ? 262144 : 32768;
    const float* s = (y == 0) ? Wv : (y == 1) ? Wqv : (y == 2) ? Wq : Wk;
    unsigned short* d = (y == 0) ? oV : (y == 1) ? oQV : (y == 2) ? oQ : oK;
    int i = (blockIdx.x * 256 + threadIdx.x) * 4;
    if (i < n) {
        float4 v = *(const float4*)(s + i);
        ushort4v o = { f2bf(v.x), f2bf(v.y), f2bf(v.z), f2bf(v.w) };
        *(ushort4v*)(d + i) = o;
    }
}

// ---------------- x fp32 [C][P] -> xT bf16 [P][C], both tensors ----------------
__global__ __launch_bounds__(256) void cast_transpose_cp(
    const float* __restrict__ xq, const float* __restrict__ xe,
    unsigned short* __restrict__ xTq, unsigned short* __restrict__ xTe)
{
    int zz = blockIdx.z;
    int which = zz & 1;
    size_t b = zz >> 1;
    const float* xb = (which ? xe : xq) + b * (size_t)CP;
    unsigned short* xTb = (which ? xTe : xTq) + b * (size_t)CP;
    int p0 = blockIdx.x * 64, c0 = blockIdx.y * 64;

    __shared__ unsigned short T[64][65];
    int t = threadIdx.x;
    int pp = t & 31, cg = t >> 5;
#pragma unroll
    for (int i = 0; i < 8; ++i) {
        int c = cg + 8 * i;
        float2v v = *(const float2v*)(xb + (size_t)(c0 + c) * PP + p0 + pp * 2);
        T[c][pp * 2] = f2bf(v.x);
        T[c][pp * 2 + 1] = f2bf(v.y);
    }
    __syncthreads();
    int cp = t & 31;
#pragma unroll
    for (int i = 0; i < 8; ++i) {
        int e = t + 256 * i;
        int p = e >> 5;
        ushort2v o = { T[cp * 2][p], T[cp * 2 + 1][p] };
        *(ushort2v*)(xTb + (size_t)(p0 + p) * C_ + c0 + cp * 2) = o;
    }
}

// ---------------- MFMA GEMM q & k (BM=64, bf16 out), counted-vmcnt 2-phase ----------------
// grid (72, 2, g); per-tile VMEM instrs/wave = 3 (1 A + 2 B)
__global__ __launch_bounds__(256) void gemm_qk(
    const unsigned short* __restrict__ Wqb, const unsigned short* __restrict__ Wkb,
    const unsigned short* __restrict__ xTq, const unsigned short* __restrict__ xTe,
    const float* __restrict__ bq, const float* __restrict__ bk,
    unsigned short* __restrict__ qout, unsigned short* __restrict__ kout)
{
    int sel = blockIdx.y;
    const unsigned short* A = sel ? Wkb : Wqb;
    const float* bias = sel ? bk : bq;
    int p0 = blockIdx.x * 128;
    size_t b = blockIdx.z;
    const unsigned short* Bb = (sel ? xTe : xTq) + b * (size_t)CP;
    unsigned short* outb = (sel ? kout : qout) + b * (size_t)C8P;

    __shared__ __align__(16) unsigned short Asm[2][64 * 32];
    __shared__ __align__(16) unsigned short Bsm[2][128 * 32];

    int tid = threadIdx.x;
    int lane = tid & 63, wid = tid >> 6;
    int wr = wid >> 1, wc = wid & 1;
    int l15 = lane & 15, l4 = lane >> 4;
    f32x4 acc[2][4] = {};

#define QK_STAGE(KT, BUF)                                                              \
    {                                                                                  \
        int k0s = (KT) * 32;                                                           \
        int c = tid;                                                                   \
        gload16(A + (size_t)(c >> 2) * 512 + k0s + (c & 3) * 8, Asm[BUF] + c * 8);     \
        gload16(Bb + (size_t)(p0 + (c >> 2)) * 512 + k0s + (c & 3) * 8, Bsm[BUF] + c * 8); \
        int cb = tid + 256;                                                            \
        gload16(Bb + (size_t)(p0 + (cb >> 2)) * 512 + k0s + (cb & 3) * 8, Bsm[BUF] + cb * 8); \
    }

    QK_STAGE(0, 0);
    QK_STAGE(1, 1);

#pragma unroll
    for (int k = 0; k < 16; ++k) {
        int cur = k & 1;
        if (k < 15) asm volatile("s_waitcnt vmcnt(3)" ::: "memory");
        else        asm volatile("s_waitcnt vmcnt(0)" ::: "memory");
        __builtin_amdgcn_s_barrier();
        bf16x8 af[2], bfr[4];
#pragma unroll
        for (int m = 0; m < 2; ++m)
            af[m] = *(const bf16x8*)&Asm[cur][(wr * 32 + m * 16 + l15) * 32 + l4 * 8];
#pragma unroll
        for (int n = 0; n < 4; ++n)
            bfr[n] = *(const bf16x8*)&Bsm[cur][(wc * 64 + n * 16 + l15) * 32 + l4 * 8];
#pragma unroll
        for (int m = 0; m < 2; ++m)
#pragma unroll
            for (int n = 0; n < 4; ++n)
                acc[m][n] = __builtin_amdgcn_mfma_f32_16x16x32_bf16(af[m], bfr[n], acc[m][n], 0, 0, 0);
        asm volatile("" ::: "memory");
        __builtin_amdgcn_s_barrier();
        if (k < 14) QK_STAGE(k + 2, cur);
    }
#undef QK_STAGE

#pragma unroll
    for (int m = 0; m < 2; ++m)
#pragma unroll
        for (int n = 0; n < 4; ++n) {
            int pcol = p0 + wc * 64 + n * 16 + l15;
#pragma unroll
            for (int r = 0; r < 4; ++r) {
                int orow = wr * 32 + m * 16 + l4 * 4 + r;
                outb[(size_t)orow * PP + pcol] = f2bf(acc[m][n][r] + bias[orow]);
            }
        }
}

// ---------------- bf16 96x96 spatial transpose (q,k only) ----------------
__global__ __launch_bounds__(256) void thw_b(
    const unsigned short* __restrict__ in, unsigned short* __restrict__ out)
{
    size_t m = blockIdx.x;
    const unsigned short* im = in + m * (size_t)PP;
    unsigned short* om = out + m * (size_t)PP;
    __shared__ unsigned short T[96][97];
    int t = threadIdx.x;
#pragma unroll
    for (int i = 0; i < 18; ++i) {
        int v = t + 256 * i;
        int r = v / 48, pp = v - r * 48;
        ushort2v u = *(const ushort2v*)(im + r * 96 + pp * 2);
        T[r][pp * 2] = u.x;
        T[r][pp * 2 + 1] = u.y;
    }
    __syncthreads();
#pragma unroll
    for (int i = 0; i < 18; ++i) {
        int v = t + 256 * i;
        int w = v / 48, hh = v - w * 48;
        ushort2v o = { T[hh * 2][w], T[hh * 2 + 1][w] };
        *(ushort2v*)(om + w * 96 + hh * 2) = o;
    }
}

// ---------------- scores + exp + row-partial-sums: grid (96, 2, g) ----------------
__global__ __launch_bounds__(256) void scores_kernel(
    const unsigned short* __restrict__ qT, const unsigned short* __restrict__ kT,
    const unsigned short* __restrict__ q, const unsigned short* __restrict__ k,
    unsigned short* __restrict__ attb, float* __restrict__ rsum0, float* __restrict__ rsum1)
{
    int s = blockIdx.x;
    int ori = blockIdx.y;
    size_t b = blockIdx.z;
    const unsigned short* qs = (ori ? q : qT) + b * (size_t)C8P;
    const unsigned short* ks = (ori ? k : kT) + b * (size_t)C8P;
    unsigned short* ab = attb + b * (size_t)ATTN;
    float* rs = (ori ? rsum1 : rsum0) + b * (size_t)PP;

    __shared__ float Qs[64][97];
    __shared__ float Ks[64][97];
    int t = threadIdx.x;
    for (int v = t; v < 64 * 12; v += 256) {
        int c = v / 12, gg = v - c * 12;
        size_t gi = (size_t)c * PP + (size_t)s * 96 + gg * 8;
        ushort8 uq = *(const ushort8*)(qs + gi);
        ushort8 uk = *(const ushort8*)(ks + gi);
#pragma unroll
        for (int kk = 0; kk < 8; ++kk) {
            Qs[c][gg * 8 + kk] = bf2f(uq[kk]);
            Ks[c][gg * 8 + kk] = bf2f(uk[kk]);
        }
    }
    __syncthreads();
    int tx = t & 15, ty = t >> 4;
    float acc[6][6] = {};
    for (int c = 0; c < 64; ++c) {
        float qf[6], kf[6];
#pragma unroll
        for (int i = 0; i < 6; ++i) { qf[i] = Qs[c][ty + 16 * i]; kf[i] = Ks[c][tx + 16 * i]; }
#pragma unroll
        for (int i = 0; i < 6; ++i)
#pragma unroll
            for (int j = 0; j < 6; ++j) acc[i][j] = fmaf(qf[i], kf[j], acc[i][j]);
    }
#pragma unroll
    for (int i = 0; i < 6; ++i) {
        int m = ty + 16 * i;
        size_t row = ori ? ((size_t)s * 96 + m) : ((size_t)m * 96 + s);
        unsigned short* rowp = ab + row * 192 + (ori ? 96 : 0);
        float part = 0.0f;
#pragma unroll
        for (int j = 0; j < 6; ++j) {
            int jj = tx + 16 * j;
            float e = (!ori && jj == m) ? 0.0f : __expf(acc[i][j] - 20.0f);
            part += e;
            rowp[jj] = f2bf(e);
        }
#pragma unroll
        for (int off = 1; off < 16; off <<= 1) part += __shfl_xor(part, off);
        if (tx == 0) rs[row] = part;
    }
}

// ---------------- MFMA apply on x (staged from xT, XOR-swizzled): yT[p][c] ----------------
// grid (96 s, 4 = path*2+ct, g), 512 thr = 8 waves (2 m x 4 n)
template<int ORI>
__global__ __launch_bounds__(512) void apply_mfma(
    const unsigned short* __restrict__ xT_e, const unsigned short* __restrict__ xT_q,
    unsigned short* __restrict__ yT_e, unsigned short* __restrict__ yT_q,
    const unsigned short* __restrict__ attb,
    const float* __restrict__ rsum0, const float* __restrict__ rsum1)
{
    int s = blockIdx.x;
    int path = blockIdx.y >> 1, ct = blockIdx.y & 1;
    int c0 = ct * 256;
    size_t b = blockIdx.z;
    const unsigned short* X = (path ? xT_q : xT_e) + b * (size_t)CP;
    unsigned short* Y = (path ? yT_q : yT_e) + b * (size_t)CP;
    const unsigned short* ab = attb + b * (size_t)ATTN;
    const float* r0 = rsum0 + b * (size_t)PP;
    const float* r1 = rsum1 + b * (size_t)PP;

    __shared__ __align__(16) unsigned short Att[96][104];
    __shared__ __align__(16) unsigned short Xs[256][104];   // [c][j], col-group XOR-swizzled by (c>>3)&3

    int tid = threadIdx.x;
    for (int v = tid; v < 96 * 12; v += 512) {
        int r = v / 12, gg = v - r * 12;
        size_t base = ORI ? ((size_t)(s * 96 + r) * 192 + 96) : ((size_t)(r * 96 + s) * 192);
        *(ushort8*)&Att[r][gg * 8] = *(const ushort8*)(ab + base + gg * 8);
    }
    for (int v = tid; v < 96 * 32; v += 512) {
        int j = v >> 5, cc = v & 31;
        size_t pj = ORI ? ((size_t)s * 96 + j) : ((size_t)j * 96 + s);
        ushort8 u = *(const ushort8*)(X + pj * C_ + c0 + cc * 8);
        int js = j ^ ((cc & 3) << 3);
#pragma unroll
        for (int e = 0; e < 8; ++e) Xs[cc * 8 + e][js] = u[e];
    }
    __syncthreads();

    int lane = tid & 63, wid = tid >> 6;
    int wm = wid >> 2, wn = wid & 3;
    int l15 = lane & 15, l4 = lane >> 4;
    f32x4 acc[3][4] = {};
#pragma unroll
    for (int k = 0; k < 3; ++k) {
        bf16x8 a[3], xx[4];
#pragma unroll
        for (int mi = 0; mi < 3; ++mi)
            a[mi] = *(const bf16x8*)&Att[wm * 48 + mi * 16 + l15][k * 32 + l4 * 8];
#pragma unroll
        for (int ni = 0; ni < 4; ++ni) {
            int row = wn * 64 + ni * 16 + l15;
            int gsw = (k * 4 + l4) ^ ((row >> 3) & 3);
            xx[ni] = *(const bf16x8*)&Xs[row][gsw * 8];
        }
#pragma unroll
        for (int mi = 0; mi < 3; ++mi)
#pragma unroll
            for (int ni = 0; ni < 4; ++ni)
                acc[mi][ni] = __builtin_amdgcn_mfma_f32_16x16x32_bf16(a[mi], xx[ni], acc[mi][ni], 0, 0, 0);
    }

#pragma unroll
    for (int mi = 0; mi < 3; ++mi) {
#pragma unroll
        for (int r = 0; r < 4; ++r) {
            int mrow = wm * 48 + mi * 16 + l4 * 4 + r;
            size_t p = ORI ? ((size_t)s * 96 + mrow) : ((size_t)mrow * 96 + s);
            float rinv = 0.0f;
            if (ORI) rinv = 1.0f / (r0[p] + r1[p]);
            size_t base = p * C_ + c0;
#pragma unroll
            for (int ni = 0; ni < 4; ++ni) {
                size_t idx = base + wn * 64 + ni * 16 + l15;
                if (ORI == 0) {
                    Y[idx] = f2bf(acc[mi][ni][r]);
                } else {
                    float tot = bf2f(Y[idx]) + acc[mi][ni][r];
                    Y[idx] = f2bf(tot * rinv);
                }
            }
        }
    }
}

// ---------------- final GEMM + fused epilogue: 512 thr, BK=64, swizzle, counted-vmcnt dbuf ----------------
// grid (72, 8, g); y = path*4 + ot; per-tile VMEM instrs/wave = 4
__global__ __launch_bounds__(512) void gemm_out(
    const unsigned short* __restrict__ Wvb, const unsigned short* __restrict__ Wqvb,
    const unsigned short* __restrict__ yT_e, const unsigned short* __restrict__ yT_q,
    const float* __restrict__ bv, const float* __restrict__ bqv,
    const float* __restrict__ xe, const float* __restrict__ xq,
    const float* __restrict__ g1, const float* __restrict__ g2,
    float* __restrict__ o0, float* __restrict__ o1)
{
    int yy = blockIdx.y;
    int path = yy >> 2, ot = yy & 3;
    const unsigned short* A = path ? Wqvb : Wvb;
    const float* bias = path ? bqv : bv;
    int p0 = blockIdx.x * 128;
    int o0r = ot * 128;
    size_t b = blockIdx.z;
    const unsigned short* Bb = (path ? yT_q : yT_e) + b * (size_t)CP;
    const float* xb = (path ? xq : xe) + b * (size_t)CP;
    float* ob = (path ? o1 : o0) + b * (size_t)CP;
    float gam = (path ? g2 : g1)[0];

    __shared__ __align__(16) unsigned short Asm[2][128 * 64];
    __shared__ __align__(16) unsigned short Bsm[2][128 * 64];

    int tid = threadIdx.x;             // 0..511, 8 waves
    int lane = tid & 63, wid = tid >> 6;
    int wr = wid >> 2, wc = wid & 3;   // 2 x 4 wave grid; wave tile 64 rows x 32 cols
    int l15 = lane & 15, l4 = lane >> 4;
    f32x4 acc[4][2] = {};

#define GO_STAGE(KT, BUF)                                                                  \
    {                                                                                      \
        int k0s = (KT) * 64;                                                               \
        _Pragma("unroll")                                                                  \
        for (int i = 0; i < 2; ++i) {                                                      \
            int ch = tid + i * 512;                                                        \
            int row = ch >> 3, slot = ch & 7;                                              \
            int gs = slot ^ (row & 7);                                                     \
            gload16(A + (size_t)(o0r + row) * 512 + k0s + gs * 8, Asm[BUF] + ch * 8);      \
            gload16(Bb + (size_t)(p0 + row) * 512 + k0s + gs * 8, Bsm[BUF] + ch * 8);      \
        }                                                                                  \
    }

    GO_STAGE(0, 0);
    GO_STAGE(1, 1);

#pragma unroll
    for (int k = 0; k < 8; ++k) {
        int cur = k & 1;
        if (k < 7) asm volatile("s_waitcnt vmcnt(4)" ::: "memory");
        else       asm volatile("s_waitcnt vmcnt(0)" ::: "memory");
        __builtin_amdgcn_s_barrier();
#pragma unroll
        for (int ks = 0; ks < 2; ++ks) {
            bf16x8 af[4], bfr[2];
#pragma unroll
            for (int m = 0; m < 4; ++m) {
                int row = wr * 64 + m * 16 + l15;
                int sl = (ks * 4 + l4) ^ (row & 7);
                af[m] = *(const bf16x8*)&Asm[cur][row * 64 + sl * 8];
            }
#pragma unroll
            for (int n = 0; n < 2; ++n) {
                int row = wc * 32 + n * 16 + l15;
                int sl = (ks * 4 + l4) ^ (row & 7);
                bfr[n] = *(const bf16x8*)&Bsm[cur][row * 64 + sl * 8];
            }
#pragma unroll
            for (int m = 0; m < 4; ++m)
#pragma unroll
                for (int n = 0; n < 2; ++n)
                    acc[m][n] = __builtin_amdgcn_mfma_f32_16x16x32_bf16(af[m], bfr[n], acc[m][n], 0, 0, 0);
        }
        asm volatile("" ::: "memory");
        __builtin_amdgcn_s_barrier();
        if (k < 6) GO_STAGE(k + 2, cur);
    }
#undef GO_STAGE

#pragma unroll
    for (int m = 0; m < 4; ++m)
#pragma unroll
        for (int n = 0; n < 2; ++n) {
            int pcol = p0 + wc * 32 + n * 16 + l15;
#pragma unroll
            for (int r = 0; r < 4; ++r) {
                int orow = o0r + wr * 64 + m * 16 + l4 * 4 + r;
                size_t idx = (size_t)orow * PP + pcol;
                float val = acc[m][n][r] + bias[orow];
                ob[idx] = gam * (val + 2.0f) + xb[idx];
            }
        }
}

extern "C" void kernel_launch(void* const* d_in, const int* in_sizes, int n_in,
                              void* d_out, int out_size, void* d_ws, size_t ws_size,
                              hipStream_t stream)
{
    const float* x_ex = (const float*)d_in[0];
    const float* x_q  = (const float*)d_in[1];
    const float* Wq   = (const float*)d_in[2];
    const float* bq   = (const float*)d_in[3];
    const float* Wk   = (const float*)d_in[4];
    const float* bk   = (const float*)d_in[5];
    const float* Wv   = (const float*)d_in[6];
    const float* bv   = (const float*)d_in[7];
    const float* Wqv  = (const float*)d_in[8];
    const float* bqv  = (const float*)d_in[9];
    const float* g1   = (const float*)d_in[10];
    const float* g2   = (const float*)d_in[11];
    float* out0 = (float*)d_out;
    float* out1 = out0 + (size_t)8 * CP;

    unsigned short* hp = (unsigned short*)d_ws;
    unsigned short* Wvb  = hp; hp += 262144;
    unsigned short* Wqvb = hp; hp += 262144;
    unsigned short* Wqb  = hp; hp += 32768;
    unsigned short* Wkb  = hp; hp += 32768;
    size_t head = (size_t)(hp - (unsigned short*)d_ws) * 2;

    size_t perB = 4ull * CP + (size_t)ATTN + 4ull * C8P + 4ull * PP;
    int g = 8;
    while (g > 1 && head + (size_t)g * perB * 2 > ws_size) g >>= 1;

    unsigned short* p = hp;
    unsigned short* xT_e = p; p += (size_t)g * CP;
    unsigned short* xT_q = p; p += (size_t)g * CP;
    unsigned short* yT_e = p; p += (size_t)g * CP;
    unsigned short* yT_q = p; p += (size_t)g * CP;
    unsigned short* attb = p; p += (size_t)g * ATTN;
    unsigned short* qb   = p; p += (size_t)g * C8P;
    unsigned short* kb   = p; p += (size_t)g * C8P;  // adjacent to qb
    unsigned short* qTb  = p; p += (size_t)g * C8P;
    unsigned short* kTb  = p; p += (size_t)g * C8P;  // adjacent to qTb
    float* rsum0 = (float*)p; p += (size_t)g * PP * 2;
    float* rsum1 = (float*)p; p += (size_t)g * PP * 2;

    cast_w<<<dim3(256, 4), 256, 0, stream>>>(Wv, Wqv, Wq, Wk, Wvb, Wqvb, Wqb, Wkb);

    for (int b0 = 0; b0 < 8; b0 += g) {
        const float* xe = x_ex + (size_t)b0 * CP;
        const float* xq = x_q  + (size_t)b0 * CP;
        float* o0 = out0 + (size_t)b0 * CP;
        float* o1 = out1 + (size_t)b0 * CP;

        cast_transpose_cp<<<dim3(144, 8, 2 * g), 256, 0, stream>>>(xq, xe, xT_q, xT_e);
        gemm_qk<<<dim3(72, 2, g), 256, 0, stream>>>(Wqb, Wkb, xT_q, xT_e, bq, bk, qb, kb);
        thw_b<<<dim3(2 * g * 64), 256, 0, stream>>>(qb, qTb);
        scores_kernel<<<dim3(96, 2, g), 256, 0, stream>>>(qTb, kTb, qb, kb, attb, rsum0, rsum1);
        apply_mfma<0><<<dim3(96, 4, g), 512, 0, stream>>>(xT_e, xT_q, yT_e, yT_q, attb, rsum0, rsum1);
        apply_mfma<1><<<dim3(96, 4, g), 512, 0, stream>>>(xT_e, xT_q, yT_e, yT_q, attb, rsum0, rsum1);
        gemm_out<<<dim3(72, 8, g), 512, 0, stream>>>(Wvb, Wqvb, yT_e, yT_q, bv, bqv,
                                                     xe, xq, g1, g2, o0, o1);
    }
}